// Round 18
// baseline (29.779 us; speedup 1.0000x reference)
//
#include <hip/hip_runtime.h>
#include <hip/hip_bf16.h>

// B=16, Ci=16, Co=16, H=W=24, hidden=64.
// kt:    K[dy47][dxi][o][i] bf16; dy47 = dy+23 in [0,47), dxi = dx+24 in [0,49).
//        dxi stride = 256 shorts.
// vpad2: bf16 [y'=40][x'=40][b=16][i=16], y'=h+8, x'=w+8, zero halo.
// r18: 2-kernel, direct-output conv with restored occupancy (r17 lesson:
//   144 blocks = 0.56/CU regressed; need >=252). Grid (wtc12, h24) = 288
//   blocks x 512 thr = 8 waves. Block owns row h, cols w0 = wtc*2, w0+1.
//   Wave: t = wv+8k (k<3) = H2; per t: 12 dxp x 2 ww MFMAs, B shared across
//   ww. Total MFMA = 165,888 = algebraic minimum. 8-wave LDS reduce ->
//   scale + bias -> float2 out. No atomics (r13), no coop sync (r14).

typedef __attribute__((ext_vector_type(8))) short bf16x8;
typedef __attribute__((ext_vector_type(4))) float f32x4;

#define KT_ELEMS (47*49*256)          // 589,568 bf16
#define VPAD2_ELEMS (40*40*256)       // 409,600 bf16
#define NROWS (47*49)                 // 2303 MLP rows
#define NPOS 576                      // 24*24 output positions
#define PREP_BUILD_BLOCKS 288         // ceil(2303/8)
#define PREP_PAD_BLOCKS (VPAD2_ELEMS/256)   // 1600

// ---------------- Kernel 1: prep = build K table + pad v (fused grid) -------
__launch_bounds__(256)
__global__ void prep(const float* __restrict__ v,
                     const float* __restrict__ w1, const float* __restrict__ b1,
                     const float* __restrict__ w2, const float* __restrict__ b2,
                     __hip_bfloat16* __restrict__ kt, __hip_bfloat16* __restrict__ vpad)
{
    const int tid = threadIdx.x;

    if (blockIdx.x >= PREP_BUILD_BLOCKS) {
        // ---- pad part: vpad2[y][x][b][i] ----
        int idx = (blockIdx.x - PREP_BUILD_BLOCKS)*256 + tid;
        if (idx >= VPAD2_ELEMS) return;
        int i = idx & 15;
        int b = (idx >> 4) & 15;
        int s = idx >> 8;             // y*40 + x
        int x = s % 40;
        int y = s / 40;
        int h = y - 8, w = x - 8;
        float val = 0.0f;
        if (h >= 0 && h < 24 && w >= 0 && w < 24)
            val = v[((b*16 + i)*24 + h)*24 + w];
        vpad[idx] = __float2bfloat16(val);
        return;
    }

    // ---- build part: 8 rows of the [2303 x 256] K GEMM per block ----
    __shared__ float ty_s[47];
    __shared__ float tx_s[49];
    __shared__ float hid_s[8][64];
    const int r0 = blockIdx.x * 8;

    if (tid < 47)               ty_s[tid]      = tanhf((float)(tid - 23) * (1.0f/6.0f));
    if (tid >= 64 && tid < 113) tx_s[tid - 64] = tanhf((float)(tid - 64 - 24) * (1.0f/6.0f));
    __syncthreads();

    #pragma unroll
    for (int k = 0; k < 2; ++k) {
        int idx = k*256 + tid;
        int rr  = idx >> 6;
        int j   = idx & 63;
        int r   = r0 + rr;
        if (r >= NROWS) r = NROWS - 1;
        int dy47 = r / 49;
        int dxi  = r % 49;
        float x = ty_s[dy47]*w1[2*j] + tx_s[dxi]*w1[2*j+1] + b1[j];
        hid_s[rr][j] = 0.5f*x*(1.0f + erff(x*0.70710678118f));
    }
    __syncthreads();

    const int c = tid;
    float acc[8];
    const float bb = b2[c];
    #pragma unroll
    for (int r = 0; r < 8; ++r) acc[r] = bb;

    const float4* w2v = (const float4*)w2;
    #pragma unroll
    for (int jv = 0; jv < 16; ++jv) {
        float4 wv = w2v[c*16 + jv];
        #pragma unroll
        for (int e = 0; e < 4; ++e) {
            float we = ((const float*)&wv)[e];
            int j = jv*4 + e;
            #pragma unroll
            for (int r = 0; r < 8; ++r)
                acc[r] += hid_s[r][j] * we;
        }
    }

    #pragma unroll
    for (int rr = 0; rr < 8; ++rr) {
        int r = r0 + rr;
        if (r >= NROWS) break;
        kt[r*256 + c] = __float2bfloat16(acc[rr]);
    }
}

// ---------------- Kernel 2: direct-output MFMA conv (288 blocks) ------------
// Block = (wtc, h): output row h, cols w0 = wtc*2, w0+1. Wave wv: t = wv+8k,
// k<3, t == H2; dy47 = t - h + 23 in [0,47).
// A(ww,dxp): dxi = 24 - w0 - ww + 2*dxp + d; range [1,47] subset of [0,49). OK.
// B(dxp): y' = t+8 in [8,32), x' = 8+2dxp+d in [8,32). Shared across ww.
__launch_bounds__(512)
__global__ void conv_direct(const __hip_bfloat16* __restrict__ kt_,
                            const __hip_bfloat16* __restrict__ vpad_,
                            const float* __restrict__ bias,
                            float* __restrict__ out)
{
    __shared__ f32x4 red[8][2][64];   // 16 KB; first 2 KB reused as lds2
    const short* kt = (const short*)kt_;
    const short* vp = (const short*)vpad_;

    const int wtc = blockIdx.x;       // 0..11 -> w0 = wtc*2
    const int h   = blockIdx.y;       // 0..23
    const int w0  = wtc * 2;

    const int tid  = threadIdx.x;
    const int lane = tid & 63;
    const int wv   = tid >> 6;        // 0..7
    const int n    = lane & 15;       // A: o row; B: b col
    const int g    = lane >> 4;       // k-group
    const int d    = g >> 1;          // dx sub-offset within pair
    const int ih   = (g & 1) * 8;     // i-half

    f32x4 acc[2];
    acc[0] = (f32x4){0.f,0.f,0.f,0.f};
    acc[1] = (f32x4){0.f,0.f,0.f,0.f};

    #pragma unroll
    for (int k = 0; k < 3; ++k) {
        const int t = wv + k*8;                             // = H2, 0..23
        const int dy47 = t - h + 23;                        // 0..46
        const short* apb = kt + ((long)(dy47*49 + (24 - w0 + d)))*256 + n*16 + ih;
        const short* bpb = vp + ((long)((t + 8)*40 + (8 + d)))*256 + n*16 + ih;

        // prefetch all B for this t (12 independent 16B loads)
        bf16x8 bv[12];
        #pragma unroll
        for (int dxp = 0; dxp < 12; ++dxp)
            bv[dxp] = *(const bf16x8*)(bpb + dxp*512);      // x' += 2 per dxp

        #pragma unroll
        for (int dxp = 0; dxp < 12; ++dxp) {
            bf16x8 a0 = *(const bf16x8*)(apb + (2*dxp    )*256);   // ww=0
            bf16x8 a1 = *(const bf16x8*)(apb + (2*dxp - 1)*256);   // ww=1
            acc[0] = __builtin_amdgcn_mfma_f32_16x16x32_bf16(a0, bv[dxp], acc[0], 0, 0, 0);
            acc[1] = __builtin_amdgcn_mfma_f32_16x16x32_bf16(a1, bv[dxp], acc[1], 0, 0, 0);
        }
    }

    // ---- 8-wave reduce ----
    red[wv][0][lane] = acc[0];
    red[wv][1][lane] = acc[1];
    __syncthreads();

    f32x4 s;
    if (wv < 2) {
        s = red[0][wv][lane];
        #pragma unroll
        for (int src = 1; src < 8; ++src) s += red[src][wv][lane];
    }
    __syncthreads();                  // all red reads done before lds2 overwrite

    float* lds2 = (float*)red;        // [2 ww][256 c2], 2 KB
    if (wv < 2) {
        const int c2b = n*16 + g*4;   // c2 = b*16 + o, o = g*4+e
        #pragma unroll
        for (int e = 0; e < 4; ++e) lds2[wv*256 + c2b + e] = s[e];
    }
    __syncthreads();

    if (tid < 256) {
        const float sc = 1.0f/576.0f;
        const float bb = bias[tid & 15];
        float2 o;
        o.x = lds2[0*256 + tid]*sc + bb;
        o.y = lds2[1*256 + tid]*sc + bb;
        *(float2*)(out + (size_t)tid*NPOS + h*24 + w0) = o;
    }
}

extern "C" void kernel_launch(void* const* d_in, const int* in_sizes, int n_in,
                              void* d_out, int out_size, void* d_ws, size_t ws_size,
                              hipStream_t stream)
{
    const float* v    = (const float*)d_in[0];
    const float* w1   = (const float*)d_in[1];
    const float* b1   = (const float*)d_in[2];
    const float* w2   = (const float*)d_in[3];
    const float* b2   = (const float*)d_in[4];
    const float* bias = (const float*)d_in[5];
    float* out = (float*)d_out;

    char* ws = (char*)d_ws;
    __hip_bfloat16* kt   = (__hip_bfloat16*)ws;                          // 1,179,136 B
    __hip_bfloat16* vpad = (__hip_bfloat16*)(ws + (size_t)KT_ELEMS*2);   //   819,200 B

    prep<<<dim3(PREP_BUILD_BLOCKS + PREP_PAD_BLOCKS), dim3(256), 0, stream>>>(
        v, w1, b1, w2, b2, kt, vpad);
    conv_direct<<<dim3(12, 24), dim3(512), 0, stream>>>(kt, vpad, bias, out);
}

// Round 19
// 25.496 us; speedup vs baseline: 1.1680x; 1.1680x over previous
//
#include <hip/hip_runtime.h>
#include <hip/hip_bf16.h>

// B=16, Ci=16, Co=16, H=W=24, hidden=64.
// kt:    K[dy47][dxi][o][i] bf16; dy47 = dy+23 in [0,47), dxi = dx+24 in [0,49).
//        dxi stride = 256 shorts.
// vpad2: bf16 [y'=40][x'=40][b=16][i=16], y'=h+8, x'=w+8, zero halo.
// r19 = r12 (best: 25.39us) + coalesced transpose-pad (r12's pad read v at
//   stride-576/lane, ~16x overfetch). conv_part/combine byte-identical to r12.
//   Lessons kept: no atomics (r13), no coop sync (r14), sliding-A 0.5 loads/
//   MFMA (r18 regression), 252-block conv grid (r17).

typedef __attribute__((ext_vector_type(8))) short bf16x8;
typedef __attribute__((ext_vector_type(4))) float f32x4;

#define KT_ELEMS (47*49*256)          // 589,568 bf16
#define VPAD2_ELEMS (40*40*256)       // 409,600 bf16
#define NROWS (47*49)                 // 2303 MLP rows
#define NPOS 576                      // 24*24 output positions
#define NOCT 7                        // dy octets (7*4 = 28 >= 27)
#define PREP_BUILD_BLOCKS 288         // ceil(2303/8)
#define PREP_T_BLOCKS 24              // transpose tiles: 4 bi x 6 hw
#define PREP_Z_BLOCKS 16              // halo zero

// ---------------- Kernel 1: prep = build kt + transpose-pad v ---------------
__launch_bounds__(256)
__global__ void prep(const float* __restrict__ v,
                     const float* __restrict__ w1, const float* __restrict__ b1,
                     const float* __restrict__ w2, const float* __restrict__ b2,
                     __hip_bfloat16* __restrict__ kt, __hip_bfloat16* __restrict__ vpad)
{
    const int tid = threadIdx.x;
    const int bid = blockIdx.x;

    if (bid >= PREP_BUILD_BLOCKS + PREP_T_BLOCKS) {
        // ---- halo zero: 16 blocks x 100 yx rows; zero rows outside interior
        const int hb = bid - PREP_BUILD_BLOCKS - PREP_T_BLOCKS;
        if (tid < 32) {
            for (int j = 0; j < 100; ++j) {
                int yx = hb*100 + j;
                int y = yx / 40, x = yx % 40;
                if (y >= 8 && y < 32 && x >= 8 && x < 32) continue;
                bf16x8 z = {0,0,0,0,0,0,0,0};
                *(bf16x8*)((short*)vpad + (size_t)yx*256 + tid*8) = z;
            }
        }
        return;
    }

    if (bid >= PREP_BUILD_BLOCKS) {
        // ---- transpose pad: tile = 64 bi x 96 hw (4 h-rows), coalesced both ways
        __shared__ __hip_bfloat16 tile[64][98];   // 98: odd-4B stride, no conflicts
        const int tb  = bid - PREP_BUILD_BLOCKS;
        const int bi0 = (tb & 3) * 64;
        const int hw0 = (tb >> 2) * 96;           // h0 = hw0/24 (4 rows)

        #pragma unroll
        for (int it = 0; it < 24; ++it) {         // read: 96-float coalesced runs
            int idx = it*256 + tid;               // 0..6143
            int bil = idx / 96;
            int hwl = idx % 96;
            tile[bil][hwl] = __float2bfloat16(v[(size_t)(bi0 + bil)*576 + hw0 + hwl]);
        }
        __syncthreads();

        #pragma unroll
        for (int it = 0; it < 6; ++it) {          // write: short4-coalesced per yx row
            int idx  = it*256 + tid;              // 0..1535
            int yxl  = idx >> 4;                  // 0..95
            int q    = idx & 15;                  // bi quad
            int hw   = hw0 + yxl;
            int y    = hw / 24 + 8;
            int x    = hw % 24 + 8;
            short4 o;
            o.x = *(short*)&tile[q*4 + 0][yxl];
            o.y = *(short*)&tile[q*4 + 1][yxl];
            o.z = *(short*)&tile[q*4 + 2][yxl];
            o.w = *(short*)&tile[q*4 + 3][yxl];
            *(short4*)((short*)vpad + ((size_t)(y*40 + x)*256 + bi0 + q*4)) = o;
        }
        return;
    }

    // ---- build part: 8 rows of the [2303 x 256] K GEMM per block ----
    __shared__ float ty_s[47];
    __shared__ float tx_s[49];
    __shared__ float hid_s[8][64];
    const int r0 = bid * 8;

    if (tid < 47)               ty_s[tid]      = tanhf((float)(tid - 23) * (1.0f/6.0f));
    if (tid >= 64 && tid < 113) tx_s[tid - 64] = tanhf((float)(tid - 64 - 24) * (1.0f/6.0f));
    __syncthreads();

    #pragma unroll
    for (int k = 0; k < 2; ++k) {
        int idx = k*256 + tid;
        int rr  = idx >> 6;
        int j   = idx & 63;
        int r   = r0 + rr;
        if (r >= NROWS) r = NROWS - 1;
        int dy47 = r / 49;
        int dxi  = r % 49;
        float x = ty_s[dy47]*w1[2*j] + tx_s[dxi]*w1[2*j+1] + b1[j];
        hid_s[rr][j] = 0.5f*x*(1.0f + erff(x*0.70710678118f));
    }
    __syncthreads();

    const int c = tid;
    float acc[8];
    const float bb = b2[c];
    #pragma unroll
    for (int r = 0; r < 8; ++r) acc[r] = bb;

    const float4* w2v = (const float4*)w2;
    #pragma unroll
    for (int jv = 0; jv < 16; ++jv) {
        float4 wv = w2v[c*16 + jv];
        #pragma unroll
        for (int e = 0; e < 4; ++e) {
            float we = ((const float*)&wv)[e];
            int j = jv*4 + e;
            #pragma unroll
            for (int r = 0; r < 8; ++r)
                acc[r] += hid_s[r][j] * we;
        }
    }

    #pragma unroll
    for (int rr = 0; rr < 8; ++rr) {
        int r = r0 + rr;
        if (r >= NROWS) break;
        kt[r*256 + c] = __float2bfloat16(acc[rr]);
    }
}

// ---------------- Kernel 2: MFMA conv (byte-identical to r12) ----------------
// grid (wt6, hg6, oct7), 512 thr = 8 waves = (tq 0..3) x (hhh 0..1).
// A(ww,dxp): dxi = 24 - w0 - ww + 2*dxp + d; dxi stride = 256 shorts.
__launch_bounds__(512)
__global__ void conv_part(const __hip_bfloat16* __restrict__ kt_,
                          const __hip_bfloat16* __restrict__ vpad_,
                          float* __restrict__ part)
{
    __shared__ f32x4 red[8][4][64];   // [src wave][ww][lane], 32 KB
    const short* kt = (const short*)kt_;
    const short* vp = (const short*)vpad_;

    const int wt  = blockIdx.x;       // 0..5  -> w0 = wt*4
    const int hg  = blockIdx.y;       // 0..5  -> h0 = hg*4
    const int oct = blockIdx.z;       // 0..6
    const int w0  = wt * 4;
    const int h0  = hg * 4;

    const int tid  = threadIdx.x;
    const int lane = tid & 63;
    const int wv   = tid >> 6;        // 0..7
    const int tq   = wv & 3;
    const int hhh  = wv >> 2;         // h-pair of this wave
    const int n    = lane & 15;       // A: o row; B: b col
    const int g    = lane >> 4;       // k-group
    const int d    = g >> 1;          // dx sub-offset within pair
    const int ih   = (g & 1) * 8;     // i-half

    const int t = oct*4 + tq;         // dy index; dy = t - h0 - 3, valid t < 27

    f32x4 acc[2][4];
    #pragma unroll
    for (int hh = 0; hh < 2; ++hh)
        #pragma unroll
        for (int ww = 0; ww < 4; ++ww) acc[hh][ww] = (f32x4){0.f,0.f,0.f,0.f};

    if (t < 27) {
        const int dy47 = t - h0 + 20;                       // in [0,46]
        const short* apb = kt + ((long)(dy47*49 + (24 - w0 + d)))*256 + n*16 + ih;
        const short* bpb = vp + ((long)((t + hhh*2 + 5)*40 + (8 + d)))*256 + n*16 + ih;

        bf16x8 av[4];
        av[0] = *(const bf16x8*)(apb);            // ww=0: dxi base
        av[1] = *(const bf16x8*)(apb - 256);      // ww=1
        av[2] = *(const bf16x8*)(apb - 512);      // ww=2
        av[3] = *(const bf16x8*)(apb - 768);      // ww=3

        #pragma unroll
        for (int dxp = 0; dxp < 12; ++dxp) {
            bf16x8 bv0 = *(const bf16x8*)(bpb +         dxp*512);   // x' += 2/dxp
            bf16x8 bv1 = *(const bf16x8*)(bpb + 10240 + dxp*512);   // +1 y' row
            #pragma unroll
            for (int ww = 0; ww < 4; ++ww) {
                acc[0][ww] = __builtin_amdgcn_mfma_f32_16x16x32_bf16(av[ww], bv0, acc[0][ww], 0, 0, 0);
                acc[1][ww] = __builtin_amdgcn_mfma_f32_16x16x32_bf16(av[ww], bv1, acc[1][ww], 0, 0, 0);
            }
            if (dxp < 11) {
                av[2] = av[0];                    // A(2,dxp+1) = A(0,dxp)
                av[3] = av[1];                    // A(3,dxp+1) = A(1,dxp)
                av[0] = *(const bf16x8*)(apb + (2*dxp + 2)*256);
                av[1] = *(const bf16x8*)(apb + (2*dxp + 1)*256);
            }
        }
    }

    #pragma unroll
    for (int hh = 0; hh < 2; ++hh) {
        if (hh) __syncthreads();                  // protect red reuse
        #pragma unroll
        for (int ww = 0; ww < 4; ++ww) red[wv][ww][lane] = acc[hh][ww];
        __syncthreads();

        const int hhh2 = wv >> 2;
        const int ww2  = wv & 3;
        f32x4 s = red[4*hhh2 + 0][ww2][lane];
        s += red[4*hhh2 + 1][ww2][lane];
        s += red[4*hhh2 + 2][ww2][lane];
        s += red[4*hhh2 + 3][ww2][lane];

        const int h = h0 + hhh2*2 + hh;
        const int w = w0 + ww2;
        const int p = h*24 + w;
        float* dst = part + ((size_t)oct*NPOS + p)*256 + (n*16 + g*4);
        *(f32x4*)dst = s;
    }
}

// ---------------- Kernel 3: combine (byte-identical to r12) -----------------
__launch_bounds__(256)
__global__ void combine(const float* __restrict__ part, const float* __restrict__ bias,
                        float* __restrict__ out)
{
    __shared__ float lds[16][257];
    const int tid = threadIdx.x;
    const int p0  = blockIdx.x * 16;

    #pragma unroll
    for (int pp = 0; pp < 16; ++pp) {
        float s = 0.f;
        #pragma unroll
        for (int oct = 0; oct < NOCT; ++oct)
            s += part[((size_t)oct*NPOS + p0 + pp)*256 + tid];
        lds[pp][tid] = s;
    }
    __syncthreads();

    const int pp = tid & 15;
    const int g  = tid >> 4;          // 0..15 across the block
    const float sc = 1.0f/576.0f;
    #pragma unroll
    for (int cc = 0; cc < 16; ++cc) {
        int c2 = cc*16 + g;           // c2 = b*16 + o
        out[(size_t)c2*576 + p0 + pp] = lds[pp][c2]*sc + bias[c2 & 15];
    }
}

extern "C" void kernel_launch(void* const* d_in, const int* in_sizes, int n_in,
                              void* d_out, int out_size, void* d_ws, size_t ws_size,
                              hipStream_t stream)
{
    const float* v    = (const float*)d_in[0];
    const float* w1   = (const float*)d_in[1];
    const float* b1   = (const float*)d_in[2];
    const float* w2   = (const float*)d_in[3];
    const float* b2   = (const float*)d_in[4];
    const float* bias = (const float*)d_in[5];
    float* out = (float*)d_out;

    char* ws = (char*)d_ws;
    __hip_bfloat16* kt   = (__hip_bfloat16*)ws;                          // 1,179,136 B
    __hip_bfloat16* vpad = (__hip_bfloat16*)(ws + (size_t)KT_ELEMS*2);   //   819,200 B
    float* part = (float*)(ws + (size_t)KT_ELEMS*2 + (size_t)VPAD2_ELEMS*2); // 4,128,768 B

    prep<<<dim3(PREP_BUILD_BLOCKS + PREP_T_BLOCKS + PREP_Z_BLOCKS),
           dim3(256), 0, stream>>>(v, w1, b1, w2, b2, kt, vpad);
    conv_part<<<dim3(6, 6, NOCT), dim3(512), 0, stream>>>(kt, vpad, part);
    combine<<<dim3(NPOS/16), dim3(256), 0, stream>>>(part, bias, out);
}